// Round 12
// baseline (1085.833 us; speedup 1.0000x reference)
//
#include <hip/hip_runtime.h>
#include <hip/hip_bf16.h>

// SwiGLU MLP: out = down( silu(x@Wg^T + bg) * (x@Wu^T + bu) ) + bd
// M=4096 tokens, H=4096, I=11008. fp32 in/out, bf16 MFMA compute.
// GEMM: 256x256 tile, BK=64, 8 waves (2Mx4N), 2-deep LDS dbuf (128 KiB).
// SEMI-DRIFT schedule (R11): 2 sync points per K-tile (vmcnt(6)+bar, vmcnt(2)+bar);
// waves free-run within 32-MFMA chunks so LDS reads overlap MFMA cross-wave.
// R12 delta: + s_setprio(1) around each 16-MFMA burst (T5, m218b: +21-25% on
// counted-vmcnt phase-split structures). Invariant entering tile t: only t.A1
// (2 loads) outstanding. Conflict-free XOR slot-swizzle (0 conflicts, R9-verified),
// XCD-aware bijective block swizzle.

#define M_TOK 4096
#define HID   4096
#define INT_  11008

typedef __attribute__((ext_vector_type(8))) short bf16x8;
typedef __attribute__((ext_vector_type(4))) float f32x4;

__device__ __forceinline__ unsigned short f2bf(float f) {
    union { float f; unsigned int u; } a; a.f = f;
    unsigned int u = a.u;
    u += 0x7fff + ((u >> 16) & 1);   // RNE
    return (unsigned short)(u >> 16);
}

__device__ __forceinline__ float bf2f(unsigned short h) {
    union { unsigned int u; float f; } a; a.u = ((unsigned int)h) << 16;
    return a.f;
}

// ---------------- fp32 -> bf16 convert (vectorized, grid-stride) ----------------
__global__ void cvt_f32_bf16(const float* __restrict__ in, unsigned short* __restrict__ out, int n4) {
    int stride = gridDim.x * blockDim.x;
    for (int i = blockIdx.x * blockDim.x + threadIdx.x; i < n4; i += stride) {
        float4 v = ((const float4*)in)[i];
        ushort4 o;
        o.x = f2bf(v.x); o.y = f2bf(v.y); o.z = f2bf(v.z); o.w = f2bf(v.w);
        ((ushort4*)out)[i] = o;
    }
}

#define GLL(gsrc, ldst) \
    __builtin_amdgcn_global_load_lds( \
        (__attribute__((address_space(1))) void*)(gsrc), \
        (__attribute__((address_space(3))) void*)(ldst), 16, 0, 0)

// ---------------- 256x256-tile bf16 GEMM, C = A * B^T (+epilogue) ----------------
// A: M x K bf16 row-major; B: N x K bf16 row-major. M%256==0, N%256==0, K%64==0,
// grid divisible by 8.
// LDS per buffer (shorts): A-half0 [0,8192) A-half1 [8192,16384)
//                          B-half0 [16384,24576) B-half1 [24576,32768).
// A-half h = rows ((row>>6)&1)==h packed [128][64]; B-half h = cols ((col>>5)&1)==h.
// Within a row, 16B slot s stored at s^(r&7)  (R9-verified: 0 bank conflicts).
// EPI 0: bf16 (acc+bias); EPI 1: bf16 silu(g)*(acc+bias); EPI 2: fp32 (acc+bias)
template<int EPI>
__global__ __launch_bounds__(512, 2)
void gemm256(const unsigned short* __restrict__ A,
             const unsigned short* __restrict__ B,
             const float* __restrict__ bias,
             const unsigned short* __restrict__ gbuf,
             void* __restrict__ Cv,
             int M, int N, int K) {
    __shared__ unsigned short lds[2 * 32768];   // 128 KiB

    const int tid  = threadIdx.x;
    const int lane = tid & 63;
    const int w    = tid >> 6;       // wave 0..7
    const int wm   = w >> 2;         // 0..1  (M half, 128 rows)
    const int wn   = w & 3;          // 0..3  (N quarter, 64 cols)

    // XCD-aware bijective swizzle (grid % 8 == 0)
    const int ntn = N >> 8;
    const int chunk = gridDim.x >> 3;
    const int sw = (blockIdx.x & 7) * chunk + (blockIdx.x >> 3);
    const int bm = sw / ntn, bn = sw % ntn;

    const unsigned short* Ag = A + (size_t)(bm * 256) * K;
    const unsigned short* Bg = B + (size_t)(bn * 256) * K;

    // ---- staging source offsets (pre-swizzled; LDS dest linear) ----
    int offA[2][2], offB[2][2];
#pragma unroll
    for (int h = 0; h < 2; ++h)
#pragma unroll
        for (int i = 0; i < 2; ++i) {
            int sig = i * 512 + tid;
            int r   = sig >> 3;            // packed row 0..127
            int s   = (sig & 7) ^ (r & 7); // logical 16B slot
            int grow = ((r >> 6) * 2 + h) * 64 + (r & 63);   // A global row
            int gcol = ((r >> 5) * 2 + h) * 32 + (r & 31);   // B global N-col
            offA[h][i] = grow * K + s * 8;
            offB[h][i] = gcol * K + s * 8;
        }

    // ---- ds_read fragment addressing (swizzled slots) ----
    const int rl = lane & 15;
    const int kg = lane >> 4;
    const int x  = rl & 7;
    const int aRow = (wm * 64 + rl) * 64;
    const int bRow = 16384 + (wn * 32 + rl) * 64;
    int slt[2];
#pragma unroll
    for (int ks = 0; ks < 2; ++ks) slt[ks] = ((ks * 4 + kg) ^ x) * 8;

    f32x4 acc[2][2][8];
#pragma unroll
    for (int qm = 0; qm < 2; ++qm)
#pragma unroll
        for (int qn = 0; qn < 2; ++qn)
#pragma unroll
            for (int f = 0; f < 8; ++f)
                acc[qm][qn][f] = (f32x4){0.f, 0.f, 0.f, 0.f};

    const int NT = K >> 6;

#define STAGE_A(H, DST, SRC) \
    GLL((SRC) + offA[H][0], (DST) + (H) * 8192 + tid * 8); \
    GLL((SRC) + offA[H][1], (DST) + (H) * 8192 + 4096 + tid * 8)
#define STAGE_B(H, DST, SRC) \
    GLL((SRC) + offB[H][0], (DST) + 16384 + (H) * 8192 + tid * 8); \
    GLL((SRC) + offB[H][1], (DST) + 16384 + (H) * 8192 + 4096 + tid * 8)

#define RD_A(BUF, QM, DST) \
    { _Pragma("unroll") for (int ks = 0; ks < 2; ++ks) \
      _Pragma("unroll") for (int fm = 0; fm < 4; ++fm) \
        DST[ks * 4 + fm] = *(const bf16x8*)((BUF) + (QM) * 8192 + aRow + fm * 1024 + slt[ks]); }
#define RD_B(BUF, QN, DST) \
    { _Pragma("unroll") for (int ks = 0; ks < 2; ++ks) \
      _Pragma("unroll") for (int fn = 0; fn < 2; ++fn) \
        DST[ks * 2 + fn] = *(const bf16x8*)((BUF) + (QN) * 8192 + bRow + fn * 1024 + slt[ks]); }
#define Q16(QM, QN, AF, BF) \
    { __builtin_amdgcn_s_setprio(1); \
      _Pragma("unroll") for (int ks = 0; ks < 2; ++ks) \
      _Pragma("unroll") for (int fm = 0; fm < 4; ++fm) \
      _Pragma("unroll") for (int fn = 0; fn < 2; ++fn) \
        acc[QM][QN][fm * 2 + fn] = __builtin_amdgcn_mfma_f32_16x16x32_bf16( \
            AF[ks * 4 + fm], BF[ks * 2 + fn], acc[QM][QN][fm * 2 + fn], 0, 0, 0); \
      __builtin_amdgcn_s_setprio(0); }
#define VMC(n) asm volatile("s_waitcnt vmcnt(" #n ")" ::: "memory")
#define BARR __builtin_amdgcn_s_barrier()
#define PIN  __builtin_amdgcn_sched_barrier(0)

    // persistent fragment registers (all statically indexed)
    bf16x8 A0f[8], A1f[8], B0f[4], B1f[4];

    // ---- prologue: stage tile 0 as A0,B0,B1,A1; establish invariant ----
    STAGE_A(0, lds, Ag); STAGE_B(0, lds, Bg); STAGE_B(1, lds, Bg); STAGE_A(1, lds, Ag);
    VMC(2);                                 // A0,B0,B1 landed; only t0.A1 in flight
    BARR; PIN;

    // ---- main loop: 2 chunks/tile, semi-drift, counted waits ----
    for (int t = 0; t < NT; ++t) {
        const unsigned short* bc = lds + (t & 1) * 32768;
        unsigned short* sb = lds + ((t + 1) & 1) * 32768;
        const int ts = (t + 1 < NT) ? (t + 1) : (NT - 1);   // clamped tail re-stage
        const unsigned short* sAt = Ag + (size_t)ts * 64;
        const unsigned short* sBt = Bg + (size_t)ts * 64;

        // ---- chunk 1: A0,B0,B1 proven; 32 MFMA; stage A0,B0,B1(t+1) ----
        RD_A(bc, 0, A0f);
        RD_B(bc, 0, B0f);
        STAGE_A(0, sb, sAt);
        Q16(0, 0, A0f, B0f);
        RD_B(bc, 1, B1f);
        STAGE_B(0, sb, sBt);
        Q16(0, 1, A0f, B1f);
        STAGE_B(1, sb, sBt);
        VMC(6);                             // retires t.A1 (leaves t+1.A0,B0,B1)
        BARR; PIN;

        // ---- chunk 2: A1 proven; 32 MFMA; stage A1(t+1) ----
        RD_A(bc, 1, A1f);
        STAGE_A(1, sb, sAt);
        Q16(1, 1, A1f, B1f);
        Q16(1, 0, A1f, B0f);
        VMC(2);                             // retires t+1.A0,B0,B1 (leaves t+1.A1)
        BARR; PIN;
    }
#undef RD_A
#undef RD_B
#undef Q16
#undef VMC
#undef BARR
#undef PIN
#undef STAGE_A
#undef STAGE_B

    // ---- epilogue: C/D layout col=lane&15, row=(lane>>4)*4+j  [m89-verified] ----
    const int rbase = bm * 256 + wm * 128 + (lane >> 4) * 4;
    const int cbase = bn * 256 + wn * 64 + (lane & 15);
#pragma unroll
    for (int qm = 0; qm < 2; ++qm)
#pragma unroll
        for (int qn = 0; qn < 2; ++qn)
#pragma unroll
            for (int fn = 0; fn < 2; ++fn) {
                const int col = cbase + qn * 32 + fn * 16;
                const float bv = bias[col];
#pragma unroll
                for (int fm = 0; fm < 4; ++fm) {
                    const int rb = rbase + qm * 64 + fm * 16;
#pragma unroll
                    for (int j = 0; j < 4; ++j) {
                        const size_t idx = (size_t)(rb + j) * (size_t)N + col;
                        float v = acc[qm][qn][fm * 2 + fn][j] + bv;
                        if (EPI == 0) {
                            ((unsigned short*)Cv)[idx] = f2bf(v);
                        } else if (EPI == 1) {
                            float g = bf2f(gbuf[idx]);
                            float s = g / (1.f + __expf(-g));   // silu(g)
                            ((unsigned short*)Cv)[idx] = f2bf(s * v);
                        } else {
                            ((float*)Cv)[idx] = v;
                        }
                    }
                }
            }
}

// ---------------- launcher ----------------
extern "C" void kernel_launch(void* const* d_in, const int* in_sizes, int n_in,
                              void* d_out, int out_size, void* d_ws, size_t ws_size,
                              hipStream_t stream) {
    const float* x  = (const float*)d_in[0];   // (2,2048,4096)
    const float* wg = (const float*)d_in[1];   // (11008,4096)
    const float* bg = (const float*)d_in[2];
    const float* wu = (const float*)d_in[3];
    const float* bu = (const float*)d_in[4];
    const float* wd = (const float*)d_in[5];   // (4096,11008)
    const float* bd = (const float*)d_in[6];

    const size_t NX = (size_t)M_TOK * HID;     // 16,777,216
    const size_t NW = (size_t)INT_ * HID;      // 45,088,768 (== M_TOK*INT_)

    unsigned short* ws = (unsigned short*)d_ws;
    unsigned short* Xb = ws;                   // x bf16
    unsigned short* S1 = Xb + NX;              // Wg -> later t
    unsigned short* S2 = S1 + NW;              // g  -> later Wd
    unsigned short* S3 = S2 + NW;              // Wu
    // peak ws need: (NX + 3*NW)*2 = 304,087,040 bytes

    dim3 blk512(512);
    dim3 blk256(256);
    const int CG = 2048;

    cvt_f32_bf16<<<CG, blk256, 0, stream>>>(x,  Xb, (int)(NX / 4));
    cvt_f32_bf16<<<CG, blk256, 0, stream>>>(wg, S1, (int)(NW / 4));
    // gate: g = x @ Wg^T + bg  (bf16 -> S2)   grid 16*43=688 (%8==0)
    gemm256<0><<<dim3(16 * 43), blk512, 0, stream>>>(Xb, S1, bg, (const unsigned short*)nullptr,
                                                     (void*)S2, M_TOK, INT_, HID);
    cvt_f32_bf16<<<CG, blk256, 0, stream>>>(wu, S3, (int)(NW / 4));
    // up + fuse: t = silu(g) * (x @ Wu^T + bu)  (bf16 -> S1, Wg dead)
    gemm256<1><<<dim3(16 * 43), blk512, 0, stream>>>(Xb, S3, bu, S2,
                                                     (void*)S1, M_TOK, INT_, HID);
    cvt_f32_bf16<<<CG, blk256, 0, stream>>>(wd, S2, (int)(NW / 4));
    // down: out = t @ Wd^T + bd  (fp32 -> d_out)  grid 16*16=256 (%8==0), NT=172
    gemm256<2><<<dim3(16 * 16), blk512, 0, stream>>>(S1, S2, bd, (const unsigned short*)nullptr,
                                                     d_out, M_TOK, HID, INT_);
}

// Round 13
// 1013.195 us; speedup vs baseline: 1.0717x; 1.0717x over previous
//
#include <hip/hip_runtime.h>
#include <hip/hip_bf16.h>

// SwiGLU MLP: out = down( silu(x@Wg^T + bg) * (x@Wu^T + bu) ) + bd
// M=4096 tokens, H=4096, I=11008. fp32 in/out, bf16 MFMA compute.
// R13: FUSED gate+up kernel (tile 256Mx128I, both gemms share staged A; silu*mul
// in-register; no g round-trip) + R11 semi-drift schedule (2 sync/tile, counted
// vmcnt, NO setprio — R12 showed it hurts here). Down-GEMM = R11 verbatim.
// Conflict-free XOR slot-swizzle (0 conflicts, R9-verified), XCD-aware swizzle.

#define M_TOK 4096
#define HID   4096
#define INT_  11008

typedef __attribute__((ext_vector_type(8))) short bf16x8;
typedef __attribute__((ext_vector_type(4))) float f32x4;

__device__ __forceinline__ unsigned short f2bf(float f) {
    union { float f; unsigned int u; } a; a.f = f;
    unsigned int u = a.u;
    u += 0x7fff + ((u >> 16) & 1);   // RNE
    return (unsigned short)(u >> 16);
}

__device__ __forceinline__ float bf2f(unsigned short h) {
    union { unsigned int u; float f; } a; a.u = ((unsigned int)h) << 16;
    return a.f;
}

// ---------------- fp32 -> bf16 convert (vectorized, grid-stride) ----------------
__global__ void cvt_f32_bf16(const float* __restrict__ in, unsigned short* __restrict__ out, int n4) {
    int stride = gridDim.x * blockDim.x;
    for (int i = blockIdx.x * blockDim.x + threadIdx.x; i < n4; i += stride) {
        float4 v = ((const float4*)in)[i];
        ushort4 o;
        o.x = f2bf(v.x); o.y = f2bf(v.y); o.z = f2bf(v.z); o.w = f2bf(v.w);
        ((ushort4*)out)[i] = o;
    }
}

#define GLL(gsrc, ldst) \
    __builtin_amdgcn_global_load_lds( \
        (__attribute__((address_space(1))) void*)(gsrc), \
        (__attribute__((address_space(3))) void*)(ldst), 16, 0, 0)

#define VMC(n) asm volatile("s_waitcnt vmcnt(" #n ")" ::: "memory")
#define BARR __builtin_amdgcn_s_barrier()
#define PIN  __builtin_amdgcn_sched_barrier(0)

// ================= FUSED gate+up: t = silu(x@Wg^T+bg) * (x@Wu^T+bu) =============
// x: M x K bf16 row-major; Wg,Wu: I x K bf16 row-major; out t: M x I bf16.
// Tile 256(M) x 128(I), BK=64, 8 waves (2Mx4N; per-wave 128x32, both gemms).
// LDS/buffer (shorts): A-half0 [0,8192) A-half1 [8192,16384)
//                      Bg [16384,24576)  Bu [24576,32768).  dbuf = 128 KiB.
// A-half h = rows ((row>>6)&1)==h packed [128][64]; Bg/Bu packed [128][64].
// Within a row, 16B slot s stored at s^(r&7) (0 bank conflicts, R9-verified).
__global__ __launch_bounds__(512, 2)
void gemm_gu(const unsigned short* __restrict__ A,
             const unsigned short* __restrict__ Wg,
             const unsigned short* __restrict__ Wu,
             const float* __restrict__ bg,
             const float* __restrict__ bu,
             unsigned short* __restrict__ T,
             int M, int NI, int K) {
    __shared__ unsigned short lds[2 * 32768];   // 128 KiB

    const int tid  = threadIdx.x;
    const int lane = tid & 63;
    const int w    = tid >> 6;
    const int wm   = w >> 2;         // 0..1  (128 rows)
    const int wn   = w & 3;          // 0..3  (32 inter-cols)

    // XCD-aware bijective swizzle (grid % 8 == 0)
    const int ntn = NI >> 7;                    // 86
    const int chunk = gridDim.x >> 3;
    const int sw = (blockIdx.x & 7) * chunk + (blockIdx.x >> 3);
    const int bm = sw / ntn, bn = sw % ntn;

    const unsigned short* Ag  = A  + (size_t)(bm * 256) * K;
    const unsigned short* Bgg = Wg + (size_t)(bn * 128) * K;
    const unsigned short* Bug = Wu + (size_t)(bn * 128) * K;

    // staging source offsets (pre-swizzled; LDS dest linear)
    int offA[2][2], offBW[2];
#pragma unroll
    for (int i = 0; i < 2; ++i) {
        int sig = i * 512 + tid;
        int r   = sig >> 3;            // packed row 0..127
        int s   = (sig & 7) ^ (r & 7); // logical 16B slot
#pragma unroll
        for (int h = 0; h < 2; ++h) {
            int grow = ((r >> 6) * 2 + h) * 64 + (r & 63);
            offA[h][i] = grow * K + s * 8;
        }
        offBW[i] = r * K + s * 8;      // B rows map 1:1
    }

    // ds_read fragment addressing (swizzled slots)
    const int rl = lane & 15;
    const int kg = lane >> 4;
    const int x  = rl & 7;
    const int aRow  = (wm * 64 + rl) * 64;
    const int bGoff = 16384 + (wn * 32 + rl) * 64;
    const int bUoff = 24576 + (wn * 32 + rl) * 64;
    int slt[2];
#pragma unroll
    for (int ks = 0; ks < 2; ++ks) slt[ks] = ((ks * 4 + kg) ^ x) * 8;

    f32x4 accg[2][8], accu[2][8];     // [qm][fm*2+fn]
#pragma unroll
    for (int q = 0; q < 2; ++q)
#pragma unroll
        for (int f = 0; f < 8; ++f) {
            accg[q][f] = (f32x4){0.f, 0.f, 0.f, 0.f};
            accu[q][f] = (f32x4){0.f, 0.f, 0.f, 0.f};
        }

    const int NT = K >> 6;

#define STAGE_A(H, DST, SRC) \
    GLL((SRC) + offA[H][0], (DST) + (H) * 8192 + tid * 8); \
    GLL((SRC) + offA[H][1], (DST) + (H) * 8192 + 4096 + tid * 8)
#define STAGE_W(BASE, DST, SRC) \
    GLL((SRC) + offBW[0], (DST) + (BASE) + tid * 8); \
    GLL((SRC) + offBW[1], (DST) + (BASE) + 4096 + tid * 8)

#define RD_A(BUF, QM, DST) \
    { _Pragma("unroll") for (int ks = 0; ks < 2; ++ks) \
      _Pragma("unroll") for (int fm = 0; fm < 4; ++fm) \
        DST[ks * 4 + fm] = *(const bf16x8*)((BUF) + (QM) * 8192 + aRow + fm * 1024 + slt[ks]); }
#define RD_W(BUF, ROFF, DST) \
    { _Pragma("unroll") for (int ks = 0; ks < 2; ++ks) \
      _Pragma("unroll") for (int fn = 0; fn < 2; ++fn) \
        DST[ks * 2 + fn] = *(const bf16x8*)((BUF) + (ROFF) + fn * 1024 + slt[ks]); }
#define Q16(ACC, QM, AF, BF) \
    { _Pragma("unroll") for (int ks = 0; ks < 2; ++ks) \
      _Pragma("unroll") for (int fm = 0; fm < 4; ++fm) \
      _Pragma("unroll") for (int fn = 0; fn < 2; ++fn) \
        ACC[QM][fm * 2 + fn] = __builtin_amdgcn_mfma_f32_16x16x32_bf16( \
            AF[ks * 4 + fm], BF[ks * 2 + fn], ACC[QM][fm * 2 + fn], 0, 0, 0); }

    bf16x8 A0f[8], A1f[8], Bgf[4], Buf_[4];

    // prologue: stage tile 0 as A0,Bg,Bu,A1; establish invariant (only A1 in flight)
    STAGE_A(0, lds, Ag);
    STAGE_W(16384, lds, Bgg);
    STAGE_W(24576, lds, Bug);
    STAGE_A(1, lds, Ag);
    VMC(2);
    BARR; PIN;

    for (int t = 0; t < NT; ++t) {
        const unsigned short* bc = lds + (t & 1) * 32768;
        unsigned short* sb = lds + ((t + 1) & 1) * 32768;
        const int ts = (t + 1 < NT) ? (t + 1) : (NT - 1);
        const unsigned short* sA = Ag + (size_t)ts * 64;
        const unsigned short* sG = Bgg + (size_t)ts * 64;
        const unsigned short* sU = Bug + (size_t)ts * 64;

        // chunk1: A0,Bg,Bu proven; 32 MFMA; stage A0,Bg,Bu(t+1)
        RD_A(bc, 0, A0f);
        RD_W(bc, bGoff, Bgf);
        STAGE_A(0, sb, sA);
        Q16(accg, 0, A0f, Bgf);
        RD_W(bc, bUoff, Buf_);
        STAGE_W(16384, sb, sG);
        Q16(accu, 0, A0f, Buf_);
        STAGE_W(24576, sb, sU);
        VMC(6);                         // retires t.A1
        BARR; PIN;

        // chunk2: A1 proven; 32 MFMA; stage A1(t+1)
        RD_A(bc, 1, A1f);
        STAGE_A(1, sb, sA);
        Q16(accg, 1, A1f, Bgf);
        Q16(accu, 1, A1f, Buf_);
        VMC(2);                         // retires t+1.A0,Bg,Bu
        BARR; PIN;
    }
#undef RD_A
#undef RD_W
#undef Q16
#undef STAGE_A
#undef STAGE_W

    // epilogue: C/D layout col=lane&15, row=(lane>>4)*4+j; t = silu(g)*u -> bf16
    const int rbase = bm * 256 + wm * 128 + (lane >> 4) * 4;
    const int cbase = bn * 128 + wn * 32 + (lane & 15);
#pragma unroll
    for (int qm = 0; qm < 2; ++qm)
#pragma unroll
        for (int fn = 0; fn < 2; ++fn) {
            const int col = cbase + fn * 16;
            const float bgv = bg[col];
            const float buv = bu[col];
#pragma unroll
            for (int fm = 0; fm < 4; ++fm) {
                const int rb = rbase + qm * 64 + fm * 16;
#pragma unroll
                for (int j = 0; j < 4; ++j) {
                    float g = accg[qm][fm * 2 + fn][j] + bgv;
                    float u = accu[qm][fm * 2 + fn][j] + buv;
                    float s = g / (1.f + __expf(-g)) * u;
                    T[(size_t)(rb + j) * (size_t)INT_ + col] = f2bf(s);
                }
            }
        }
}

// ================= down GEMM (R11 verbatim, fp32 epilogue) ======================
// A: M x K bf16 row-major; B: N x K bf16 row-major; C fp32 = A*B^T + bias.
__global__ __launch_bounds__(512, 2)
void gemm_dn(const unsigned short* __restrict__ A,
             const unsigned short* __restrict__ B,
             const float* __restrict__ bias,
             float* __restrict__ C,
             int M, int N, int K) {
    __shared__ unsigned short lds[2 * 32768];   // 128 KiB

    const int tid  = threadIdx.x;
    const int lane = tid & 63;
    const int w    = tid >> 6;
    const int wm   = w >> 2;
    const int wn   = w & 3;

    const int ntn = N >> 8;
    const int chunk = gridDim.x >> 3;
    const int sw = (blockIdx.x & 7) * chunk + (blockIdx.x >> 3);
    const int bm = sw / ntn, bn = sw % ntn;

    const unsigned short* Ag = A + (size_t)(bm * 256) * K;
    const unsigned short* Bg = B + (size_t)(bn * 256) * K;

    int offA[2][2], offB[2][2];
#pragma unroll
    for (int h = 0; h < 2; ++h)
#pragma unroll
        for (int i = 0; i < 2; ++i) {
            int sig = i * 512 + tid;
            int r   = sig >> 3;
            int s   = (sig & 7) ^ (r & 7);
            int grow = ((r >> 6) * 2 + h) * 64 + (r & 63);
            int gcol = ((r >> 5) * 2 + h) * 32 + (r & 31);
            offA[h][i] = grow * K + s * 8;
            offB[h][i] = gcol * K + s * 8;
        }

    const int rl = lane & 15;
    const int kg = lane >> 4;
    const int x  = rl & 7;
    const int aRow = (wm * 64 + rl) * 64;
    const int bRow = 16384 + (wn * 32 + rl) * 64;
    int slt[2];
#pragma unroll
    for (int ks = 0; ks < 2; ++ks) slt[ks] = ((ks * 4 + kg) ^ x) * 8;

    f32x4 acc[2][2][8];
#pragma unroll
    for (int qm = 0; qm < 2; ++qm)
#pragma unroll
        for (int qn = 0; qn < 2; ++qn)
#pragma unroll
            for (int f = 0; f < 8; ++f)
                acc[qm][qn][f] = (f32x4){0.f, 0.f, 0.f, 0.f};

    const int NT = K >> 6;

#define STAGE_A(H, DST, SRC) \
    GLL((SRC) + offA[H][0], (DST) + (H) * 8192 + tid * 8); \
    GLL((SRC) + offA[H][1], (DST) + (H) * 8192 + 4096 + tid * 8)
#define STAGE_B(H, DST, SRC) \
    GLL((SRC) + offB[H][0], (DST) + 16384 + (H) * 8192 + tid * 8); \
    GLL((SRC) + offB[H][1], (DST) + 16384 + (H) * 8192 + 4096 + tid * 8)
#define RD_A(BUF, QM, DST) \
    { _Pragma("unroll") for (int ks = 0; ks < 2; ++ks) \
      _Pragma("unroll") for (int fm = 0; fm < 4; ++fm) \
        DST[ks * 4 + fm] = *(const bf16x8*)((BUF) + (QM) * 8192 + aRow + fm * 1024 + slt[ks]); }
#define RD_B(BUF, QN, DST) \
    { _Pragma("unroll") for (int ks = 0; ks < 2; ++ks) \
      _Pragma("unroll") for (int fn = 0; fn < 2; ++fn) \
        DST[ks * 2 + fn] = *(const bf16x8*)((BUF) + (QN) * 8192 + bRow + fn * 1024 + slt[ks]); }
#define Q16(QM, QN, AF, BF) \
    { _Pragma("unroll") for (int ks = 0; ks < 2; ++ks) \
      _Pragma("unroll") for (int fm = 0; fm < 4; ++fm) \
      _Pragma("unroll") for (int fn = 0; fn < 2; ++fn) \
        acc[QM][QN][fm * 2 + fn] = __builtin_amdgcn_mfma_f32_16x16x32_bf16( \
            AF[ks * 4 + fm], BF[ks * 2 + fn], acc[QM][QN][fm * 2 + fn], 0, 0, 0); }

    bf16x8 A0f[8], A1f[8], B0f[4], B1f[4];

    STAGE_A(0, lds, Ag); STAGE_B(0, lds, Bg); STAGE_B(1, lds, Bg); STAGE_A(1, lds, Ag);
    VMC(2);
    BARR; PIN;

    for (int t = 0; t < NT; ++t) {
        const unsigned short* bc = lds + (t & 1) * 32768;
        unsigned short* sb = lds + ((t + 1) & 1) * 32768;
        const int ts = (t + 1 < NT) ? (t + 1) : (NT - 1);
        const unsigned short* sAt = Ag + (size_t)ts * 64;
        const unsigned short* sBt = Bg + (size_t)ts * 64;

        RD_A(bc, 0, A0f);
        RD_B(bc, 0, B0f);
        STAGE_A(0, sb, sAt);
        Q16(0, 0, A0f, B0f);
        RD_B(bc, 1, B1f);
        STAGE_B(0, sb, sBt);
        Q16(0, 1, A0f, B1f);
        STAGE_B(1, sb, sBt);
        VMC(6);
        BARR; PIN;

        RD_A(bc, 1, A1f);
        STAGE_A(1, sb, sAt);
        Q16(1, 1, A1f, B1f);
        Q16(1, 0, A1f, B0f);
        VMC(2);
        BARR; PIN;
    }
#undef RD_A
#undef RD_B
#undef Q16
#undef STAGE_A
#undef STAGE_B

    const int rbase = bm * 256 + wm * 128 + (lane >> 4) * 4;
    const int cbase = bn * 256 + wn * 64 + (lane & 15);
#pragma unroll
    for (int qm = 0; qm < 2; ++qm)
#pragma unroll
        for (int qn = 0; qn < 2; ++qn)
#pragma unroll
            for (int fn = 0; fn < 2; ++fn) {
                const int col = cbase + qn * 32 + fn * 16;
                const float bv = bias[col];
#pragma unroll
                for (int fm = 0; fm < 4; ++fm) {
                    const int rb = rbase + qm * 64 + fm * 16;
#pragma unroll
                    for (int j = 0; j < 4; ++j)
                        C[(size_t)(rb + j) * (size_t)N + col] = acc[qm][qn][fm * 2 + fn][j] + bv;
                }
            }
}

// ---------------- launcher ----------------
extern "C" void kernel_launch(void* const* d_in, const int* in_sizes, int n_in,
                              void* d_out, int out_size, void* d_ws, size_t ws_size,
                              hipStream_t stream) {
    const float* x  = (const float*)d_in[0];   // (2,2048,4096)
    const float* wg = (const float*)d_in[1];   // (11008,4096)
    const float* bg = (const float*)d_in[2];
    const float* wu = (const float*)d_in[3];
    const float* bu = (const float*)d_in[4];
    const float* wd = (const float*)d_in[5];   // (4096,11008)
    const float* bd = (const float*)d_in[6];

    const size_t NX = (size_t)M_TOK * HID;     // 16,777,216
    const size_t NW = (size_t)INT_ * HID;      // 45,088,768 (== M_TOK*INT_)

    unsigned short* ws = (unsigned short*)d_ws;
    unsigned short* Xb = ws;                   // x bf16
    unsigned short* S1 = Xb + NX;              // Wg bf16 -> later Wd bf16
    unsigned short* S2 = S1 + NW;              // Wu bf16
    unsigned short* S3 = S2 + NW;              // t = silu(g)*u bf16
    // peak ws need: (NX + 3*NW)*2 = 304,087,040 bytes (same as prior rounds)

    dim3 blk512(512);
    dim3 blk256(256);
    const int CG = 2048;

    cvt_f32_bf16<<<CG, blk256, 0, stream>>>(x,  Xb, (int)(NX / 4));
    cvt_f32_bf16<<<CG, blk256, 0, stream>>>(wg, S1, (int)(NW / 4));
    cvt_f32_bf16<<<CG, blk256, 0, stream>>>(wu, S2, (int)(NW / 4));
    // fused gate+up: t = silu(x@Wg^T+bg)*(x@Wu^T+bu)  grid 16*86=1376 (%8==0)
    gemm_gu<<<dim3(16 * 86), blk512, 0, stream>>>(Xb, S1, S2, bg, bu, S3,
                                                  M_TOK, INT_, HID);
    cvt_f32_bf16<<<CG, blk256, 0, stream>>>(wd, S1, (int)(NW / 4));   // Wg dead
    // down: out = t @ Wd^T + bd  (fp32)  grid 16*16=256 (%8==0), NT=172
    gemm_dn<<<dim3(16 * 16), blk512, 0, stream>>>(S3, S1, bd, (float*)d_out,
                                                  M_TOK, HID, INT_);
}